// Round 2
// baseline (179.189 us; speedup 1.0000x reference)
//
#include <hip/hip_runtime.h>

// VectorQuantiser on MI355X — register-resident rows + scalar-broadcast codebook.
// x: [32,32,32,256] f32. Row n = (b*256+c)*16+g; element d lives at
// linear = b*262144 + g*16384 + d*256 + c  (contiguous slab per (b,g)).
// emb: [64][512] f32 (d-major). dist-reduced = e2[k] - 2*dot (x2 dropped:
// constant per row, argmin-invariant; R1 validated fp-order robustness).
//
// Main kernel: 2048 blocks x 256 thr (4 waves). Lane owns one row (64 VGPR);
// wave w scans codes [w*128, w*128+128) in groups of 16 via wave-uniform
// s_load of emb (SGPR operand to v_fmac) -> no LDS, no barriers in main loop.
// Cross-wave argmin combine via tiny LDS, then epilogue writes both outputs.

#define NELEM0 8388608
#define FLTMAX 3.402823466e38f

__global__ void e2_prep_kernel(const float* __restrict__ emb, float* __restrict__ e2) {
    int k = blockIdx.x * 256 + threadIdx.x;   // grid 2 x 256 = 512 codes
    float s = 0.0f;
    #pragma unroll 8
    for (int d = 0; d < 64; ++d) {
        float v = emb[d * 512 + k];           // coalesced across k
        s = fmaf(v, v, s);
    }
    e2[k] = s;
}

template <bool USE_WS>
__global__ __launch_bounds__(256, 4)
void vq_main(const float* __restrict__ x, const float* __restrict__ meanp,
             const float* __restrict__ sdp, const float* __restrict__ emb,
             const float* __restrict__ e2w,
             float* __restrict__ out, float* __restrict__ outIdx)
{
    __shared__ float red_v[4][64];
    __shared__ int   red_i[4][64];
    __shared__ int   fin[64];
    __shared__ float e2s[512];                 // fallback only

    const int tid  = threadIdx.x;
    const int lane = tid & 63;
    const int wid  = __builtin_amdgcn_readfirstlane(tid >> 6);  // wave-uniform!

    const int blk = blockIdx.x;                // 2048 = 32 b x 16 g x 4 cq
    const int cq  = blk & 3;
    const int g   = (blk >> 2) & 15;
    const int b   = blk >> 6;
    const int c0  = cq * 64;

    const float mean = meanp[0];
    const float sd   = sdp[0];
    const bool  sdz  = (sd == 0.0f);
    const float safe = sdz ? 1.0f : sd;

    if constexpr (!USE_WS) {
        // e2 into LDS once per block, coalesced float2 reads
        float s0 = 0.0f, s1 = 0.0f;
        for (int d = 0; d < 64; ++d) {
            float2 v = *reinterpret_cast<const float2*>(&emb[d * 512 + tid * 2]);
            s0 = fmaf(v.x, v.x, s0);
            s1 = fmaf(v.y, v.y, s1);
        }
        e2s[tid * 2]     = s0;
        e2s[tid * 2 + 1] = s1;
        __syncthreads();
    }

    // ---- load & standardise this lane's row into registers ----
    const size_t base = (size_t)b * 262144 + (size_t)g * 16384 + (size_t)c0 + lane;
    float xr[64];
    #pragma unroll
    for (int d = 0; d < 64; ++d) {
        float v = x[base + (size_t)d * 256];   // coalesced: lanes stride 1
        xr[d] = (sdz ? 0.0f : v / safe) - mean;
    }

    // ---- argmin over this wave's 128 codes, 16 codes per group ----
    float bestv = FLTMAX;
    int   besti = 0;
    const int kw = wid * 128;

    for (int grp = 0; grp < 8; ++grp) {
        const int k0 = kw + grp * 16;          // wave-uniform

        float acc[16];
        #pragma unroll
        for (int j = 0; j < 16; ++j) acc[j] = 0.0f;

        #pragma unroll
        for (int d = 0; d < 64; ++d) {
            const float4* ep = reinterpret_cast<const float4*>(&emb[d * 512 + k0]);
            const float4 q0 = ep[0], q1 = ep[1], q2 = ep[2], q3 = ep[3];
            const float ev[16] = {q0.x, q0.y, q0.z, q0.w,  q1.x, q1.y, q1.z, q1.w,
                                  q2.x, q2.y, q2.z, q2.w,  q3.x, q3.y, q3.z, q3.w};
            #pragma unroll
            for (int j = 0; j < 16; ++j)
                acc[j] = fmaf(xr[d], ev[j], acc[j]);   // SGPR * VGPR + VGPR
        }

        float e2a[16];
        if constexpr (USE_WS) {
            const float4* wp = reinterpret_cast<const float4*>(&e2w[k0]);
            const float4 w0 = wp[0], w1 = wp[1], w2 = wp[2], w3 = wp[3];
            const float t[16] = {w0.x, w0.y, w0.z, w0.w,  w1.x, w1.y, w1.z, w1.w,
                                 w2.x, w2.y, w2.z, w2.w,  w3.x, w3.y, w3.z, w3.w};
            #pragma unroll
            for (int j = 0; j < 16; ++j) e2a[j] = t[j];
        } else {
            const float4* wp = reinterpret_cast<const float4*>(&e2s[k0]);
            const float4 w0 = wp[0], w1 = wp[1], w2 = wp[2], w3 = wp[3];
            const float t[16] = {w0.x, w0.y, w0.z, w0.w,  w1.x, w1.y, w1.z, w1.w,
                                 w2.x, w2.y, w2.z, w2.w,  w3.x, w3.y, w3.z, w3.w};
            #pragma unroll
            for (int j = 0; j < 16; ++j) e2a[j] = t[j];
        }

        #pragma unroll
        for (int j = 0; j < 16; ++j) {
            float v = fmaf(-2.0f, acc[j], e2a[j]);     // e2 - 2*dot
            if (v < bestv) { bestv = v; besti = k0 + j; }  // first-occurrence
        }
    }

    // ---- cross-wave combine (waves in ascending k; strict < keeps first) ----
    red_v[wid][lane] = bestv;
    red_i[wid][lane] = besti;
    __syncthreads();
    if (wid == 0) {
        float bv = bestv;
        int   bi = besti;
        #pragma unroll
        for (int w = 1; w < 4; ++w) {
            float v = red_v[w][lane];
            int   i = red_i[w][lane];
            if (v < bv) { bv = v; bi = i; }
        }
        fin[lane] = bi;
    }
    __syncthreads();
    const int kbest = fin[lane];

    // ---- outputs: each wave writes 16 d-slices of the quantised tensor ----
    #pragma unroll
    for (int dd = 0; dd < 16; ++dd) {
        const int d = wid * 16 + dd;
        const size_t go = base + (size_t)d * 256;
        float xv = x[go];
        float q  = emb[d * 512 + kbest];       // gather, L2-resident
        q = (q + mean) * sd;
        out[go] = xv + (q - xv);               // straight-through, mirrors ref order
    }
    if (wid == 0) {
        const int n = b * 4096 + (c0 + lane) * 16 + g;
        outIdx[n] = (float)kbest;
    }
}

extern "C" void kernel_launch(void* const* d_in, const int* in_sizes, int n_in,
                              void* d_out, int out_size, void* d_ws, size_t ws_size,
                              hipStream_t stream) {
    const float* x    = (const float*)d_in[0];
    const float* mean = (const float*)d_in[1];
    const float* sd   = (const float*)d_in[2];
    const float* emb  = (const float*)d_in[3];
    float* out    = (float*)d_out;
    float* outIdx = out + NELEM0;

    if (ws_size >= 512 * sizeof(float)) {
        float* e2 = (float*)d_ws;
        e2_prep_kernel<<<dim3(2), dim3(256), 0, stream>>>(emb, e2);
        vq_main<true><<<dim3(2048), dim3(256), 0, stream>>>(x, mean, sd, emb, e2, out, outIdx);
    } else {
        vq_main<false><<<dim3(2048), dim3(256), 0, stream>>>(x, mean, sd, emb, nullptr, out, outIdx);
    }
}

// Round 3
// 75.652 us; speedup vs baseline: 2.3686x; 2.3686x over previous
//
#include <hip/hip_runtime.h>

// VectorQuantiser via f16-split MFMA (full (xh+xl)(eh+el) product, K=256 logical).
// x: [32,32,32,256] f32; row n=(b*256+c)*16+g; elem d at linear b*262144+g*16384+d*256+c.
// emb: [64][512] f32. dist = e2[k] - 2*dot (x2 dropped: argmin-invariant, validated R2).
// Block: (b,g,chalf) -> 128 rows x 512 codes; 4 waves (2 row-halves x 2 code-halves);
// wave tile 64x64, 4x4 16x16x32_f16 frags, K-split via LDS address mapping.

typedef _Float16 f16;
typedef _Float16 f16x8 __attribute__((ext_vector_type(8)));
typedef float    f32x4 __attribute__((ext_vector_type(4)));

#define NELEM0 8388608
#define FLTMAX 3.402823466e38f
// ws: [0,131072) ecvt f16[512][128] ([eh(64)|el(64)] per code); [131072,133120) e2 f32[512]
#define WS_NEED 133120

__global__ void prep_kernel(const float* __restrict__ emb, f16* __restrict__ ecvt,
                            float* __restrict__ e2g) {
    const int code = blockIdx.x * 256 + threadIdx.x;   // 512 total
    f16x8 hv[8], lv[8];
    float s = 0.0f;
    #pragma unroll
    for (int d = 0; d < 64; ++d) {
        float v = emb[d * 512 + code];                 // coalesced across codes
        s = fmaf(v, v, s);
        f16 h = (f16)v;
        hv[d >> 3][d & 7] = h;
        lv[d >> 3][d & 7] = (f16)(v - (float)h);
    }
    f16* dst = ecvt + code * 128;
    #pragma unroll
    for (int j = 0; j < 8; ++j) {
        *reinterpret_cast<f16x8*>(dst + j * 8)      = hv[j];
        *reinterpret_cast<f16x8*>(dst + 64 + j * 8) = lv[j];
    }
    e2g[code] = s;
}

// LDS tiles: [row][128 f16], XOR-swizzled: f16 index = row*128 + (koff ^ ((row&7)<<3)).
__device__ __forceinline__ int swz(int row, int koff) {
    return row * 128 + (koff ^ ((row & 7) << 3));
}

template <bool USE_WS>
__global__ __launch_bounds__(256, 2)
void vq_mfma(const float* __restrict__ x, const float* __restrict__ meanp,
             const float* __restrict__ sdp, const float* __restrict__ emb,
             const f16* __restrict__ ecvt, const float* __restrict__ e2g,
             float* __restrict__ out, float* __restrict__ outIdx)
{
    __shared__ __align__(16) f16 xa[128 * 128];   // [xh(64)|xl(64)] per row
    __shared__ __align__(16) f16 es[128 * 128];   // [eh(64)|el(64)] per code (chunk)
    __shared__ float e2s[512];
    __shared__ float red_v[2][128];
    __shared__ int   red_i[2][128];
    __shared__ int   kb[128];

    const int tid  = threadIdx.x;
    const int lane = tid & 63;
    const int wid  = tid >> 6;
    const int wr   = wid >> 1;       // row half (64 rows)
    const int wc   = wid & 1;        // code half within chunk (64 codes)
    const int lr   = lane & 15;
    const int lk   = lane >> 4;

    const int blk   = blockIdx.x;    // 1024 = 32 b x 16 g x 2 chalf
    const int chalf = blk & 1;
    const int g     = (blk >> 1) & 15;
    const int b     = blk >> 5;

    const float mean = meanp[0];
    const float sd   = sdp[0];
    const bool  sdz  = (sd == 0.0f);
    const float safe = sdz ? 1.0f : sd;

    const int xbase = b * 262144 + g * 16384 + chalf * 128;

    // ---- stage A: standardise + fp16 hi/lo split, swizzled LDS ----
    {
        const int c_ = tid & 127;            // row
        const int dh = tid >> 7;             // d half (32 each)
        const float* src = x + xbase + c_;
        f16x8 hi[4], lo[4];
        #pragma unroll
        for (int jv = 0; jv < 4; ++jv)
            #pragma unroll
            for (int e = 0; e < 8; ++e) {
                int d = dh * 32 + jv * 8 + e;
                float v = src[d * 256];       // coalesced: lanes = consecutive c
                float s = (sdz ? 0.0f : v / safe) - mean;
                f16 h = (f16)s;
                hi[jv][e] = h;
                lo[jv][e] = (f16)(s - (float)h);
            }
        #pragma unroll
        for (int jv = 0; jv < 4; ++jv) {
            *reinterpret_cast<f16x8*>(&xa[swz(c_, dh * 32 + jv * 8)])      = hi[jv];
            *reinterpret_cast<f16x8*>(&xa[swz(c_, 64 + dh * 32 + jv * 8)]) = lo[jv];
        }
    }

    // ---- e2 into LDS ----
    if constexpr (USE_WS) {
        float2 v = *reinterpret_cast<const float2*>(&e2g[tid * 2]);
        e2s[tid * 2] = v.x; e2s[tid * 2 + 1] = v.y;
    } else {
        float s0 = 0.0f, s1 = 0.0f;
        for (int d = 0; d < 64; ++d) {
            float2 v = *reinterpret_cast<const float2*>(&emb[d * 512 + tid * 2]);
            s0 = fmaf(v.x, v.x, s0);
            s1 = fmaf(v.y, v.y, s1);
        }
        e2s[tid * 2] = s0; e2s[tid * 2 + 1] = s1;
    }

    float bestv[16];
    int   besti[16];
    #pragma unroll
    for (int s = 0; s < 16; ++s) { bestv[s] = FLTMAX; besti[s] = 0; }

    for (int ch = 0; ch < 4; ++ch) {
        __syncthreads();   // es reuse + xa/e2s visibility on ch==0

        if constexpr (USE_WS) {
            const f16* src = ecvt + (ch * 128) * 128;
            const int slot = tid & 15;
            const int cl0  = tid >> 4;
            #pragma unroll
            for (int i = 0; i < 8; ++i) {
                int cl = i * 16 + cl0;
                f16x8 v = *reinterpret_cast<const f16x8*>(&src[cl * 128 + slot * 8]);
                *reinterpret_cast<f16x8*>(&es[swz(cl, slot * 8)]) = v;
            }
        } else {
            const int cl = tid & 127;
            const int dh = tid >> 7;
            const float* src = emb + ch * 128 + cl;
            f16x8 hi[4], lo[4];
            #pragma unroll
            for (int jv = 0; jv < 4; ++jv)
                #pragma unroll
                for (int e = 0; e < 8; ++e) {
                    int d = dh * 32 + jv * 8 + e;
                    float v = src[d * 512];   // coalesced: lanes = consecutive codes
                    f16 h = (f16)v;
                    hi[jv][e] = h;
                    lo[jv][e] = (f16)(v - (float)h);
                }
            #pragma unroll
            for (int jv = 0; jv < 4; ++jv) {
                *reinterpret_cast<f16x8*>(&es[swz(cl, dh * 32 + jv * 8)])      = hi[jv];
                *reinterpret_cast<f16x8*>(&es[swz(cl, 64 + dh * 32 + jv * 8)]) = lo[jv];
            }
        }
        __syncthreads();

        // ---- 64x64 wave tile, K=256 logical over stored 128 ----
        f32x4 acc[4][4];
        #pragma unroll
        for (int fi = 0; fi < 4; ++fi)
            #pragma unroll
            for (int fj = 0; fj < 4; ++fj)
                acc[fi][fj] = (f32x4){0.f, 0.f, 0.f, 0.f};

        #pragma unroll
        for (int eh2 = 0; eh2 < 2; ++eh2) {          // e part: eh / el
            #pragma unroll
            for (int dh2 = 0; dh2 < 2; ++dh2) {      // d sub-range (32)
                const int kb_ = eh2 * 64 + dh2 * 32 + lk * 8;
                f16x8 bf[4];
                #pragma unroll
                for (int fj = 0; fj < 4; ++fj)
                    bf[fj] = *reinterpret_cast<const f16x8*>(
                        &es[swz(wc * 64 + fj * 16 + lr, kb_)]);
                #pragma unroll
                for (int ah = 0; ah < 2; ++ah) {     // x part: xh / xl
                    const int ka_ = ah * 64 + dh2 * 32 + lk * 8;
                    f16x8 af[4];
                    #pragma unroll
                    for (int fi = 0; fi < 4; ++fi)
                        af[fi] = *reinterpret_cast<const f16x8*>(
                            &xa[swz(wr * 64 + fi * 16 + lr, ka_)]);
                    #pragma unroll
                    for (int fi = 0; fi < 4; ++fi)
                        #pragma unroll
                        for (int fj = 0; fj < 4; ++fj)
                            acc[fi][fj] = __builtin_amdgcn_mfma_f32_16x16x32_f16(
                                af[fi], bf[fj], acc[fi][fj], 0, 0, 0);
                }
            }
        }

        // ---- distances + running argmin (codes ascend: first-occurrence) ----
        #pragma unroll
        for (int fj = 0; fj < 4; ++fj) {
            const int code_l = wc * 64 + fj * 16 + lr;
            const int codeg  = ch * 128 + code_l;
            const float e2v  = e2s[codeg];
            #pragma unroll
            for (int fi = 0; fi < 4; ++fi)
                #pragma unroll
                for (int r = 0; r < 4; ++r) {
                    float vd = fmaf(-2.0f, acc[fi][fj][r], e2v);
                    const int s = fi * 4 + r;
                    if (vd < bestv[s]) { bestv[s] = vd; besti[s] = codeg; }
                }
        }
    }

    // ---- wave-internal reduce across the 16 col-lanes (same rows) ----
    #pragma unroll
    for (int s = 0; s < 16; ++s) {
        float v = bestv[s]; int i = besti[s];
        #pragma unroll
        for (int m = 1; m < 16; m <<= 1) {
            float v2 = __shfl_xor(v, m, 64);
            int   i2 = __shfl_xor(i, m, 64);
            if (v2 < v || (v2 == v && i2 < i)) { v = v2; i = i2; }
        }
        bestv[s] = v; besti[s] = i;
    }
    if (lr == 0) {
        #pragma unroll
        for (int fi = 0; fi < 4; ++fi)
            #pragma unroll
            for (int r = 0; r < 4; ++r) {
                int row = wr * 64 + fi * 16 + lk * 4 + r;   // C/D layout row
                red_v[wc][row] = bestv[fi * 4 + r];
                red_i[wc][row] = besti[fi * 4 + r];
            }
    }
    __syncthreads();
    if (tid < 128) {
        float v0 = red_v[0][tid], v1 = red_v[1][tid];
        int   i0 = red_i[0][tid], i1 = red_i[1][tid];
        kb[tid] = (v1 < v0 || (v1 == v0 && i1 < i0)) ? i1 : i0;
    }
    __syncthreads();

    // ---- outputs ----
    float* out_ = out + xbase;
    #pragma unroll 4
    for (int i = 0; i < 32; ++i) {
        int lin = i * 256 + tid;
        int c_  = lin & 127;
        int d   = lin >> 7;
        float q = emb[d * 512 + kb[c_]];
        out_[d * 256 + c_] = (q + mean) * sd;   // == x+(q'-x) to ~1e-7
    }
    if (tid < 128) {
        int n = (b * 256 + chalf * 128 + tid) * 16 + g;
        outIdx[n] = (float)kb[tid];
    }
}

extern "C" void kernel_launch(void* const* d_in, const int* in_sizes, int n_in,
                              void* d_out, int out_size, void* d_ws, size_t ws_size,
                              hipStream_t stream) {
    const float* x    = (const float*)d_in[0];
    const float* mean = (const float*)d_in[1];
    const float* sd   = (const float*)d_in[2];
    const float* emb  = (const float*)d_in[3];
    float* out    = (float*)d_out;
    float* outIdx = out + NELEM0;

    if (ws_size >= (size_t)WS_NEED) {
        f16*   ecvt = (f16*)d_ws;
        float* e2g  = (float*)((char*)d_ws + 131072);
        prep_kernel<<<dim3(2), dim3(256), 0, stream>>>(emb, ecvt, e2g);
        vq_mfma<true><<<dim3(1024), dim3(256), 0, stream>>>(x, mean, sd, emb, ecvt, e2g, out, outIdx);
    } else {
        vq_mfma<false><<<dim3(1024), dim3(256), 0, stream>>>(x, mean, sd, emb, nullptr, nullptr, out, outIdx);
    }
}